// Round 11
// baseline (372.857 us; speedup 1.0000x reference)
//
#include <hip/hip_runtime.h>
#include <math.h>

// Problem constants (B=4, S=8192, D=1024, DG=256, E=64, K=2)
#define NTOK   32768   // B*S
#define DMODEL 1024
#define NEXP   64
#define DGENRE 256
#define BK     64      // d-chunk staged in LDS
#define TT     64      // tokens per block (one per lane)
#define NCHUNK (DMODEL / BK)

// address-space types for global_load_lds
typedef const __attribute__((address_space(1))) void ga_void;
typedef __attribute__((address_space(3))) void lds_void;

// Structure: wave = 64 tokens (one/lane) x all 64 experts; waves split D 4-way.
// FMA form: acc[e] += W[d][e] (SGPR, wave-uniform s_load) * x[d] (lane VGPR).
// W bypasses LDS and VGPRs entirely -> LDS pipe (per-CU, the R4 82us limit)
// carries only x: 1 ds_read_b128 per 256 FMAs. VALU floor = 27.3 us.
__global__ __launch_bounds__(256, 4) void moe_gate_k(
    const float* __restrict__ x, const float* __restrict__ Wx,
    const float* __restrict__ genre, const float* __restrict__ Wg,
    const float* __restrict__ bias, float* __restrict__ out) {
  // 32 KB: double-buffered x tile in main loop; reused (aliased) as the
  // cross-wave partial-logit buffer in the epilogue.
  __shared__ __align__(16) float smem[2 * TT * BK];
  __shared__ float cpart[4][NEXP];
  __shared__ float cbias[NEXP];

  const int tid  = threadIdx.x;
  const int lane = tid & 63;
  // readfirstlane: proves wave-index uniform to the compiler so W-row
  // addresses are uniform -> s_load (SMEM pipe), not per-lane VMEM.
  const int wv   = __builtin_amdgcn_readfirstlane(tid >> 6);
  const int tok0 = blockIdx.x * TT;
  const int b    = tok0 >> 13;      // tok0 / 8192; TT divides S

  // ---- genre bias partials: cbias[e] = bias[e] + genre[b,:] . Wg[:,e] ----
  {
    const int e = tid & 63, dc = tid >> 6;
    const float* g  = genre + b * DGENRE + dc * 64;
    const float* wg = Wg + (size_t)(dc * 64) * NEXP + e;
    float p = 0.f;
#pragma unroll 8
    for (int d = 0; d < 64; ++d) p = fmaf(g[d], wg[(size_t)d * NEXP], p);
    cpart[dc][e] = p;
  }

  float acc[NEXP];
#pragma unroll
  for (int e = 0; e < NEXP; ++e) acc[e] = 0.f;

  // ---- staging: chunk = 64 tok x 64 d (16 KB). Slot SL (16B) = s*256+tid;
  // token t = SL>>4, phys quad q = SL&15 holds logical d-quad (q ^ (t&7))
  // via pre-swizzled global source (both-sides-or-neither). Read bank-quad
  // = (dq ^ (lane&7)) & 7 -> 8 lanes per quad-bank, evenly pipelined.
#define STAGE(bufidx, d0)                                                      \
  {                                                                            \
    _Pragma("unroll")                                                          \
    for (int s = 0; s < 4; ++s) {                                              \
      const int SL = s * 256 + tid;                                            \
      const int t  = SL >> 4;                                                  \
      const int q  = SL & 15;                                                  \
      const int dq = q ^ (t & 7);                                              \
      const float* gsrc = x + (size_t)(tok0 + t) * DMODEL + (d0) + dq * 4;     \
      __builtin_amdgcn_global_load_lds((ga_void*)gsrc,                         \
          (lds_void*)&smem[(bufidx) * 4096 + (s * 256 + wv * 64) * 4],         \
          16, 0, 0);                                                           \
    }                                                                          \
  }

  // ---- compute: wave wv covers d in [c*64 + wv*16, +16) = 4 quads ----
#define COMPUTE(bufidx, c)                                                     \
  {                                                                            \
    _Pragma("unroll")                                                          \
    for (int r = 0; r < 4; ++r) {                                              \
      const float4 xq4 = *reinterpret_cast<const float4*>(                     \
          &smem[(bufidx) * 4096 + lane * BK +                                  \
                (((wv * 4 + r) ^ (lane & 7)) << 2)]);                          \
      const float* xa = reinterpret_cast<const float*>(&xq4);                  \
      _Pragma("unroll")                                                        \
      for (int dd = 0; dd < 4; ++dd) {                                         \
        const float* wrow =                                                    \
            Wx + (size_t)((c) * BK + wv * 16 + r * 4 + dd) * NEXP;             \
        const float xd = xa[dd];                                               \
        _Pragma("unroll")                                                      \
        for (int e = 0; e < NEXP; ++e)                                         \
          acc[e] = fmaf(xd, wrow[e], acc[e]);                                  \
      }                                                                        \
    }                                                                          \
  }

  STAGE(0, 0);
  __syncthreads();  // drains stage-0 vmcnt + covers cpart writes
  if (tid < NEXP)
    cbias[tid] = bias[tid] + cpart[0][tid] + cpart[1][tid] + cpart[2][tid] +
                 cpart[3][tid];

  for (int c = 0; c < NCHUNK; ++c) {
    if (c < NCHUNK - 1) STAGE((c + 1) & 1, (c + 1) * BK);  // issue early
    COMPUTE(c & 1, c);
    __syncthreads();
  }

  // ---- epilogue: tree-sum the 4 waves' partial logits through smem ----
  // (x buffers retired; 2-way bank aliasing on all accesses = free)
  if (wv >= 2) {
    const int base = (wv - 2) * 4096;
#pragma unroll
    for (int e = 0; e < NEXP; ++e) smem[base + e * 64 + lane] = acc[e];
  }
  __syncthreads();
  if (wv < 2) {
    const int base = wv * 4096;
#pragma unroll
    for (int e = 0; e < NEXP; ++e) acc[e] += smem[base + e * 64 + lane];
  }
  __syncthreads();
  if (wv == 1) {
#pragma unroll
    for (int e = 0; e < NEXP; ++e) smem[e * 64 + lane] = acc[e];
  }
  __syncthreads();

  if (wv == 0) {
    // final logits for token tok0+lane, fully lane-local
#pragma unroll
    for (int e = 0; e < NEXP; ++e) acc[e] += smem[e * 64 + lane] + cbias[e];

    // in-register top-2 scan; jax.lax.top_k order (value desc, index asc):
    // strict > keeps the earliest index on ties for both ranks.
    float v1 = acc[0]; int i1 = 0;
    float v2 = -INFINITY; int i2 = NEXP;
#pragma unroll
    for (int e = 1; e < NEXP; ++e) {
      const float a  = acc[e];
      const bool g1 = a > v1;
      const bool g2 = a > v2;
      const float nv2 = g1 ? v1 : (g2 ? a : v2);
      const int   ni2 = g1 ? i1 : (g2 ? e : i2);
      v1 = g1 ? a : v1;
      i1 = g1 ? e : i1;
      v2 = nv2;
      i2 = ni2;
    }

    // renormalized top-2 softmax weights: p1/(p1+p2) = 1/(1+exp(l2-l1))
    const float ew  = expf(v2 - v1);
    const float inv = 1.0f / (1.0f + ew);
    const float w1 = inv, w2 = ew * inv;

    float* gates = out + (size_t)(tok0 + lane) * NEXP;
#pragma unroll
    for (int eq = 0; eq < 16; ++eq) {
      float4 g;
      float* gp = reinterpret_cast<float*>(&g);
#pragma unroll
      for (int k = 0; k < 4; ++k) {
        const int e = eq * 4 + k;
        gp[k] = (e == i1) ? w1 : ((e == i2) ? w2 : 0.0f);
      }
      *reinterpret_cast<float4*>(&gates[eq * 4]) = g;
    }
    float* idxout = out + (size_t)NTOK * NEXP + (size_t)(tok0 + lane) * 2;
    idxout[0] = (float)i1;
    idxout[1] = (float)i2;
  }
}

extern "C" void kernel_launch(void* const* d_in, const int* in_sizes, int n_in,
                              void* d_out, int out_size, void* d_ws, size_t ws_size,
                              hipStream_t stream) {
  const float* x     = (const float*)d_in[0];
  const float* genre = (const float*)d_in[1];
  const float* Wx    = (const float*)d_in[2];
  const float* Wg    = (const float*)d_in[3];
  const float* bias  = (const float*)d_in[4];
  float* out = (float*)d_out;

  moe_gate_k<<<NTOK / TT, 256, 0, stream>>>(x, Wx, genre, Wg, bias, out);
}

// Round 12
// 229.470 us; speedup vs baseline: 1.6249x; 1.6249x over previous
//
#include <hip/hip_runtime.h>
#include <math.h>

// Problem constants (B=4, S=8192, D=1024, DG=256, E=64, K=2)
#define NTOK   32768   // B*S
#define DMODEL 1024
#define NEXP   64
#define DGENRE 256
#define BK     64      // d-chunk staged in LDS
#define TT     64      // tokens per block
#define NCHUNK (DMODEL / BK)

// address-space types for global_load_lds
typedef const __attribute__((address_space(1))) void ga_void;
typedef __attribute__((address_space(3))) void lds_void;

// jax.lax.top_k order: value descending, ties -> lower index first
__device__ __forceinline__ bool better(float va, int ia, float vb, int ib) {
  return (va > vb) || (va == vb && ia < ib);
}

// Structure: block = 64 tok x 64 exp; 4 waves SPLIT D (wave wv covers 16 d's
// per 64-d chunk). Lane tile = 8 tok x 8 exp (m=n=8): per dq-step 16
// ds_read_b128 feed 256 FMAs -> HALF of R4's LDS-instruction rate (the
// measured 82us pipe limit). Cross-wave partial-logit reduce through LDS
// (R11's measured epilogue). x swizzle: source-side dq^=tg (both-sides rule);
// W stored with expert-quad perm p=h*8+eg -> both read paths conflict-free.
__global__ __launch_bounds__(256, 2) void moe_gate_k(
    const float* __restrict__ x, const float* __restrict__ Wx,
    const float* __restrict__ genre, const float* __restrict__ Wg,
    const float* __restrict__ bias, float* __restrict__ out) {
  // 64 KB: xs dbuf = smem[0..8191], ws dbuf = smem[8192..16383].
  // Epilogue aliases smem[0..8703] after final barrier (x bufs retired).
  __shared__ __align__(16) float smem[16384];
  __shared__ float cpart[4][NEXP];
  __shared__ float cbias[NEXP];

  const int tid  = threadIdx.x;
  const int lane = tid & 63;
  const int wv   = __builtin_amdgcn_readfirstlane(tid >> 6);
  const int tg   = lane >> 3;   // token group: tokens tg*8..tg*8+7
  const int eg   = lane & 7;    // expert group: experts eg*8..eg*8+7
  const int e0   = eg * 8;
  const int tok0 = blockIdx.x * TT;
  const int b    = tok0 >> 13;  // tok0/8192; TT divides S

  // ---- genre bias partials: cbias[e] = bias[e] + genre[b,:] . Wg[:,e] ----
  {
    const int e = tid & 63, dc = tid >> 6;
    const float* g  = genre + b * DGENRE + dc * 64;
    const float* wg = Wg + (size_t)(dc * 64) * NEXP + e;
    float p = 0.f;
#pragma unroll 8
    for (int d = 0; d < 64; ++d) p = fmaf(g[d], wg[(size_t)d * NEXP], p);
    cpart[dc][e] = p;
  }

  float acc[8][8];
#pragma unroll
  for (int i = 0; i < 8; ++i)
#pragma unroll
    for (int j = 0; j < 8; ++j) acc[i][j] = 0.f;

  // ---- staging (8 gload_lds/thread/chunk) ----
  // x slot S: t=S>>4, phys q=S&15 holds logical dq = q ^ ((t>>3)&7).
  // W slot S: d=S>>4, phys p=S&15 holds expert-quad qe = ((p&7)<<1)|(p>>3)
  //   (i.e. qe=eg*2+h stored at p=h*8+eg -> 8 consecutive quad-banks/half).
#define STAGE(bufidx, d0)                                                      \
  {                                                                            \
    _Pragma("unroll")                                                          \
    for (int s = 0; s < 4; ++s) {                                              \
      const int S = s * 256 + tid;                                             \
      const int t = S >> 4, q = S & 15;                                        \
      const int dq = q ^ ((t >> 3) & 7);                                       \
      const float* gx = x + (size_t)(tok0 + t) * DMODEL + (d0) + dq * 4;       \
      __builtin_amdgcn_global_load_lds((ga_void*)gx,                           \
          (lds_void*)&smem[(bufidx) * 4096 + (s * 256 + wv * 64) * 4],         \
          16, 0, 0);                                                           \
      const int qe = ((q & 7) << 1) | (q >> 3);                                \
      const float* gw = Wx + (size_t)((d0) + t) * NEXP + qe * 4;               \
      __builtin_amdgcn_global_load_lds((ga_void*)gw,                           \
          (lds_void*)&smem[8192 + (bufidx) * 4096 + (s * 256 + wv * 64) * 4],  \
          16, 0, 0);                                                           \
    }                                                                          \
  }

  // ---- compute: wave wv handles chunk-quads Q = wv*4..wv*4+3 (16 d's) ----
#define COMPUTE(bufidx)                                                        \
  {                                                                            \
    const float* xb = &smem[(bufidx) * 4096];                                  \
    const float* wb = &smem[8192 + (bufidx) * 4096];                           \
    _Pragma("unroll")                                                          \
    for (int dq = 0; dq < 4; ++dq) {                                           \
      const int Q = wv * 4 + dq;                                               \
      float4 xv[8];                                                            \
      _Pragma("unroll")                                                        \
      for (int i = 0; i < 8; ++i)                                              \
        xv[i] = *reinterpret_cast<const float4*>(                              \
            &xb[(tg * 8 + i) * 64 + ((Q ^ tg) << 2)]);                         \
      _Pragma("unroll")                                                        \
      for (int dd = 0; dd < 4; ++dd) {                                         \
        const int d = Q * 4 + dd;                                              \
        const float4 w0 = *reinterpret_cast<const float4*>(                    \
            &wb[d * 64 + eg * 4]);                                             \
        const float4 w1 = *reinterpret_cast<const float4*>(                    \
            &wb[d * 64 + 32 + eg * 4]);                                        \
        const float* wa0 = reinterpret_cast<const float*>(&w0);                \
        const float* wa1 = reinterpret_cast<const float*>(&w1);                \
        _Pragma("unroll")                                                      \
        for (int i = 0; i < 8; ++i) {                                          \
          const float xd = reinterpret_cast<const float*>(&xv[i])[dd];         \
          _Pragma("unroll")                                                    \
          for (int j = 0; j < 4; ++j) {                                        \
            acc[i][j]     = fmaf(xd, wa0[j], acc[i][j]);                       \
            acc[i][j + 4] = fmaf(xd, wa1[j], acc[i][j + 4]);                   \
          }                                                                    \
        }                                                                      \
      }                                                                        \
    }                                                                          \
  }

  STAGE(0, 0);
  __syncthreads();  // drains stage-0 vmcnt + covers cpart writes
  if (tid < NEXP)
    cbias[tid] = bias[tid] + cpart[0][tid] + cpart[1][tid] + cpart[2][tid] +
                 cpart[3][tid];

  for (int c = 0; c < NCHUNK; ++c) {
    if (c < NCHUNK - 1) STAGE((c + 1) & 1, (c + 1) * BK);  // issue early
    COMPUTE(c & 1);
    __syncthreads();
  }

  // ---- cross-wave reduce of partial logits (68-float lane stride:
  // odd 16B-unit stride -> bank-spread, 16B-aligned for b128) ----
  if (wv >= 2) {
    float* r = &smem[(wv - 2) * 4352 + lane * 68];
#pragma unroll
    for (int i = 0; i < 8; ++i) {
      float4 t0 = {acc[i][0], acc[i][1], acc[i][2], acc[i][3]};
      float4 t1 = {acc[i][4], acc[i][5], acc[i][6], acc[i][7]};
      *reinterpret_cast<float4*>(&r[i * 8])     = t0;
      *reinterpret_cast<float4*>(&r[i * 8 + 4]) = t1;
    }
  }
  __syncthreads();
  if (wv < 2) {
    const float* r = &smem[wv * 4352 + lane * 68];
#pragma unroll
    for (int i = 0; i < 8; ++i) {
      float4 t0 = *reinterpret_cast<const float4*>(&r[i * 8]);
      float4 t1 = *reinterpret_cast<const float4*>(&r[i * 8 + 4]);
      acc[i][0] += t0.x; acc[i][1] += t0.y; acc[i][2] += t0.z; acc[i][3] += t0.w;
      acc[i][4] += t1.x; acc[i][5] += t1.y; acc[i][6] += t1.z; acc[i][7] += t1.w;
    }
  }
  __syncthreads();
  if (wv == 1) {
    float* r = &smem[lane * 68];
#pragma unroll
    for (int i = 0; i < 8; ++i) {
      float4 t0 = {acc[i][0], acc[i][1], acc[i][2], acc[i][3]};
      float4 t1 = {acc[i][4], acc[i][5], acc[i][6], acc[i][7]};
      *reinterpret_cast<float4*>(&r[i * 8])     = t0;
      *reinterpret_cast<float4*>(&r[i * 8 + 4]) = t1;
    }
  }
  __syncthreads();

  if (wv == 0) {
    const float* r = &smem[lane * 68];
    float* gates  = out;
    float* idxout = out + (size_t)NTOK * NEXP;  // topk_idx written as floats

#pragma unroll
    for (int i = 0; i < 8; ++i) {
      float4 t0 = *reinterpret_cast<const float4*>(&r[i * 8]);
      float4 t1 = *reinterpret_cast<const float4*>(&r[i * 8 + 4]);
      acc[i][0] += t0.x; acc[i][1] += t0.y; acc[i][2] += t0.z; acc[i][3] += t0.w;
      acc[i][4] += t1.x; acc[i][5] += t1.y; acc[i][6] += t1.z; acc[i][7] += t1.w;
#pragma unroll
      for (int j = 0; j < 8; ++j) acc[i][j] += cbias[e0 + j];

      // lane-local top-2 of 8 experts
      float v1 = acc[i][0]; int i1 = e0;
      float v2 = -INFINITY; int i2 = NEXP;
#pragma unroll
      for (int j = 1; j < 8; ++j) {
        const float a = acc[i][j]; const int ei = e0 + j;
        if (better(a, ei, v1, i1)) { v2 = v1; i2 = i1; v1 = a; i1 = ei; }
        else if (better(a, ei, v2, i2)) { v2 = a; i2 = ei; }
      }
      // butterfly merge across the 8 eg-lanes holding this token's 64 experts
#pragma unroll
      for (int m = 1; m < 8; m <<= 1) {
        const float ov1 = __shfl_xor(v1, m, 64); const int oi1 = __shfl_xor(i1, m, 64);
        const float ov2 = __shfl_xor(v2, m, 64); const int oi2 = __shfl_xor(i2, m, 64);
        if (better(v1, i1, ov1, oi1)) {
          if (better(ov1, oi1, v2, i2)) { v2 = ov1; i2 = oi1; }
        } else {
          if (better(v1, i1, ov2, oi2)) { v2 = v1; i2 = i1; }
          else                          { v2 = ov2; i2 = oi2; }
          v1 = ov1; i1 = oi1;
        }
      }
      // renormalized top-2 softmax weights: p1/(p1+p2) = 1/(1+exp(l2-l1))
      const float ew  = expf(v2 - v1);
      const float inv = 1.0f / (1.0f + ew);
      const float w1 = inv, w2 = ew * inv;

      const int tok = tok0 + tg * 8 + i;
      float4 g0, g1;
      float* gp0 = reinterpret_cast<float*>(&g0);
      float* gp1 = reinterpret_cast<float*>(&g1);
#pragma unroll
      for (int k = 0; k < 4; ++k) {
        const int ea = e0 + k, eb = e0 + 4 + k;
        gp0[k] = (ea == i1) ? w1 : ((ea == i2) ? w2 : 0.0f);
        gp1[k] = (eb == i1) ? w1 : ((eb == i2) ? w2 : 0.0f);
      }
      *reinterpret_cast<float4*>(&gates[(size_t)tok * NEXP + e0])     = g0;
      *reinterpret_cast<float4*>(&gates[(size_t)tok * NEXP + e0 + 4]) = g1;

      if (eg == 0) {
        idxout[(size_t)tok * 2 + 0] = (float)i1;
        idxout[(size_t)tok * 2 + 1] = (float)i2;
      }
    }
  }
}

extern "C" void kernel_launch(void* const* d_in, const int* in_sizes, int n_in,
                              void* d_out, int out_size, void* d_ws, size_t ws_size,
                              hipStream_t stream) {
  const float* x     = (const float*)d_in[0];
  const float* genre = (const float*)d_in[1];
  const float* Wx    = (const float*)d_in[2];
  const float* Wg    = (const float*)d_in[3];
  const float* bias  = (const float*)d_in[4];
  float* out = (float*)d_out;

  moe_gate_k<<<NTOK / TT, 256, 0, stream>>>(x, Wx, genre, Wg, bias, out);
}